// Round 1
// baseline (708.617 us; speedup 1.0000x reference)
//
#include <hip/hip_runtime.h>

#define NTAGS 48
#define NB    512
#define SLEN  2048

// ---------- cross-lane helpers (wave64, DPP-based: VALU latency, not LDS path) ----------

__device__ __forceinline__ int rl_i(int v, int l) {
  return __builtin_amdgcn_readlane(v, l);
}
__device__ __forceinline__ float rl_f(float v, int l) {
  return __builtin_bit_cast(float, __builtin_amdgcn_readlane(__builtin_bit_cast(int, v), l));
}

template <int CTRL, bool BC>
__device__ __forceinline__ float dpp_mv(float oldv, float v) {
  return __builtin_bit_cast(float, __builtin_amdgcn_update_dpp(
      __builtin_bit_cast(int, oldv), __builtin_bit_cast(int, v), CTRL, 0xF, 0xF, BC));
}

// full-wave max: row_ror 8/4/2/1 within 16-rows, then row_bcast15 + row_bcast31
// (lane 63 holds the global max; rebroadcast via readlane -> SGPR).
__device__ __forceinline__ float wred_max(float v) {
  v = fmaxf(v, dpp_mv<0x128, false>(v, v));
  v = fmaxf(v, dpp_mv<0x124, false>(v, v));
  v = fmaxf(v, dpp_mv<0x122, false>(v, v));
  v = fmaxf(v, dpp_mv<0x121, false>(v, v));
  v = fmaxf(v, dpp_mv<0x142, false>(v, v));  // bcast15: invalid lanes keep old=v (no-op for max)
  v = fmaxf(v, dpp_mv<0x143, false>(v, v));  // bcast31
  return rl_f(v, 63);
}

// full-wave sum; only lane 63 is a correct total (rocPRIM pattern) -> readlane 63.
__device__ __forceinline__ float wred_sum(float v) {
  v += dpp_mv<0x128, true>(0.0f, v);
  v += dpp_mv<0x124, true>(0.0f, v);
  v += dpp_mv<0x122, true>(0.0f, v);
  v += dpp_mv<0x121, true>(0.0f, v);
  v += dpp_mv<0x142, true>(0.0f, v);  // bound_ctrl=1: invalid lanes add 0
  v += dpp_mv<0x143, true>(0.0f, v);
  return rl_f(v, 63);
}

// ---------- scan kernel: blockIdx even = forward half, odd = backward half ----------
// One wave (64 threads) per stream; lane j holds alpha[j] (or beta[j]).
// alpha step (E-trick):  m = max(alpha); p = exp(alpha-m); alpha' = m + log(p . E_col) + emit_t
// beta  step:            x = beta + emit_t; m = max(x); q = exp(x-m); beta' = m + log(E_row . q)
// Score for the gold path is fused (uses the same emit registers via readlane).

extern "C" __global__ __launch_bounds__(64)
void crf_scan(const float* __restrict__ emis,
              const float* __restrict__ trans,
              const float* __restrict__ startt,
              const float* __restrict__ endt,
              const int*   __restrict__ tags,
              const float* __restrict__ mask,
              float* __restrict__ wa, float* __restrict__ wb,
              float* __restrict__ wsc, int* __restrict__ wcnt) {
  __shared__ __align__(16) float s_p[64];
  __shared__ float s_trans[NTAGS * NTAGS];

  const int  lane = threadIdx.x;
  const int  bid  = blockIdx.x;
  const int  b    = bid >> 1;
  const bool fwd  = (bid & 1) == 0;
  const int  jc   = lane < NTAGS ? lane : (NTAGS - 1);  // clamp pad lanes (harmless dup of 47)

  for (int k = lane; k < NTAGS * NTAGS; k += 64) s_trans[k] = trans[k];
  __syncthreads();

  // E = exp(trans): fwd lane j holds column j; bwd lane i holds row i. 48 VGPRs.
  float E[NTAGS];
  if (fwd) {
#pragma unroll
    for (int i = 0; i < NTAGS; ++i) E[i] = __expf(s_trans[i * NTAGS + jc]);
  } else {
#pragma unroll
    for (int j = 0; j < NTAGS; ++j) E[j] = __expf(s_trans[jc * NTAGS + j]);
  }

  const float* eb = emis + (size_t)b * SLEN * NTAGS;
  const int*   tb = tags + b * SLEN;
  const float* mb = mask + b * SLEN;

  float ebuf[4];          // 4-deep emission prefetch ring (slot = t & 3)
  float score = 0.0f;
  int   cnt   = 0;

  if (fwd) {
    // alpha_0 = start + emit_0 ; score init = alpha_0[tag_0]
    float alpha = startt[jc] + eb[jc];
    if (lane >= NTAGS) alpha = -1e30f;
    int tag0 = __builtin_amdgcn_readfirstlane(tb[0]);
    score = rl_f(alpha, tag0);
    if (mb[0] != 0.0f) cnt = 1;
    int prev = tag0;

#pragma unroll
    for (int k = 1; k <= 4; ++k) ebuf[k & 3] = eb[k * NTAGS + jc];

    for (int c = 0; c < 16; ++c) {          // steps t = 1 .. 1023 -> alpha_1023
      int   tch = tb[c * 64 + lane];        // 64 tags / 64 masks per chunk, coalesced
      float mch = mb[c * 64 + lane];
      int i0 = (c == 0) ? 1 : 0;
#pragma unroll 4
      for (int i = i0; i < 64; ++i) {
        const int t    = c * 64 + i;
        const int slot = t & 3;
        int   cur   = rl_i(tch, i);
        float mval  = rl_f(mch, i);
        float emitv = ebuf[slot];
        ebuf[slot] = eb[(t + 4) * NTAGS + jc];   // prefetch t+4 (stays in-bounds)
        if (mval != 0.0f) {                       // wave-uniform branch (mask all-ones here)
          score += s_trans[prev * NTAGS + cur] + rl_f(emitv, cur);
          cnt++;
          float m = wred_max(alpha);
          float p = __expf(alpha - m);            // p <= 1, pad lanes -> 0
          s_p[lane] = p;
          __builtin_amdgcn_wave_barrier();        // single wave: DS is in-order, just pin order
          const float4* pv = (const float4*)s_p;  // same-address b128 reads = broadcast
          float a0 = 0.f, a1 = 0.f, a2 = 0.f, a3 = 0.f;
#pragma unroll
          for (int k = 0; k < 12; ++k) {
            float4 pp = pv[k];
            a0 = fmaf(pp.x, E[4 * k + 0], a0);
            a1 = fmaf(pp.y, E[4 * k + 1], a1);
            a2 = fmaf(pp.z, E[4 * k + 2], a2);
            a3 = fmaf(pp.w, E[4 * k + 3], a3);
          }
          __builtin_amdgcn_wave_barrier();
          alpha = m + __logf((a0 + a1) + (a2 + a3)) + emitv;
        }
        prev = cur;
      }
    }
    if (lane < NTAGS) wa[b * NTAGS + lane] = alpha;
    if (lane == 0) { wsc[b] = score; wcnt[b] = cnt; }
  } else {
    // beta_{2047} = end ; steps t = 2047 .. 1024 -> beta_1023
    float beta = endt[jc];
    if (lane >= NTAGS) beta = -1e30f;
#pragma unroll
    for (int k = 0; k < 4; ++k) ebuf[(2047 - k) & 3] = eb[(2047 - k) * NTAGS + jc];

    for (int c = 31; c >= 16; --c) {
      int   tch = tb[c * 64 + lane];
      float mch = mb[c * 64 + lane];
      int   pb  = __builtin_amdgcn_readfirstlane(tb[c * 64 - 1]);  // chunk-boundary prev tag
#pragma unroll 4
      for (int i = 63; i >= 0; --i) {
        const int t    = c * 64 + i;
        const int slot = t & 3;
        int   cur   = rl_i(tch, i);
        int   prev  = (i > 0) ? rl_i(tch, i - 1) : pb;
        float mval  = rl_f(mch, i);
        float emitv = ebuf[slot];
        ebuf[slot] = eb[(t - 4) * NTAGS + jc];
        if (mval != 0.0f) {
          score += s_trans[prev * NTAGS + cur] + rl_f(emitv, cur);
          cnt++;
          float x = beta + emitv;                 // pad lanes stay ~ -1e30
          float m = wred_max(x);
          float q = __expf(x - m);
          s_p[lane] = q;
          __builtin_amdgcn_wave_barrier();
          const float4* pv = (const float4*)s_p;
          float a0 = 0.f, a1 = 0.f, a2 = 0.f, a3 = 0.f;
#pragma unroll
          for (int k = 0; k < 12; ++k) {
            float4 pp = pv[k];
            a0 = fmaf(pp.x, E[4 * k + 0], a0);
            a1 = fmaf(pp.y, E[4 * k + 1], a1);
            a2 = fmaf(pp.z, E[4 * k + 2], a2);
            a3 = fmaf(pp.w, E[4 * k + 3], a3);
          }
          __builtin_amdgcn_wave_barrier();
          beta = m + __logf((a0 + a1) + (a2 + a3));
        }
      }
    }
    if (lane < NTAGS) wb[b * NTAGS + lane] = beta;
    if (lane == 0) { wsc[NB + b] = score; wcnt[NB + b] = cnt; }
  }
}

// ---------- combine: partition_b = lse(alpha_mid + beta_mid); loss = mean(partition - score) ----------

extern "C" __global__ __launch_bounds__(64)
void crf_combine(const float* __restrict__ wa, const float* __restrict__ wb,
                 const float* __restrict__ wsc, const int* __restrict__ wcnt,
                 const int* __restrict__ tags, const float* __restrict__ endt,
                 float* __restrict__ out) {
  const int b    = blockIdx.x;
  const int lane = threadIdx.x;
  float v = -1e30f;
  if (lane < NTAGS) v = wa[b * NTAGS + lane] + wb[b * NTAGS + lane];
  float m = wred_max(v);
  float s = wred_sum(__expf(v - m));   // pad lanes contribute exp(-huge) = 0
  float partition = m + __logf(s);
  int   last = wcnt[b] + wcnt[NB + b] - 1;
  int   ltag = tags[b * SLEN + last];
  float score = wsc[b] + wsc[NB + b] + endt[ltag];
  if (lane == 0) atomicAdd(out, (partition - score) * (1.0f / (float)NB));
}

// ---------- launch ----------

extern "C" void kernel_launch(void* const* d_in, const int* in_sizes, int n_in,
                              void* d_out, int out_size, void* d_ws, size_t ws_size,
                              hipStream_t stream) {
  const float* emis  = (const float*)d_in[0];
  const float* trans = (const float*)d_in[1];
  const float* stt   = (const float*)d_in[2];
  const float* ent   = (const float*)d_in[3];
  const int*   tags  = (const int*)d_in[4];
  const float* mask  = (const float*)d_in[5];

  // workspace layout (re-poisoned each call; fully rewritten by crf_scan before reads)
  float* wa   = (float*)d_ws;              // [NB][NTAGS] alpha_mid
  float* wb   = wa + NB * NTAGS;           // [NB][NTAGS] beta_mid
  float* wsc  = wb + NB * NTAGS;           // [2*NB] score partials (fwd, bwd)
  int*   wcnt = (int*)(wsc + 2 * NB);      // [2*NB] mask counts

  hipMemsetAsync(d_out, 0, sizeof(float), stream);
  crf_scan<<<2 * NB, 64, 0, stream>>>(emis, trans, stt, ent, tags, mask, wa, wb, wsc, wcnt);
  crf_combine<<<NB, 64, 0, stream>>>(wa, wb, wsc, wcnt, tags, ent, (float*)d_out);
}

// Round 2
// 481.459 us; speedup vs baseline: 1.4718x; 1.4718x over previous
//
#include <hip/hip_runtime.h>

#define NTAGS 48
#define NB    512
#define SLEN  2048

typedef float v2f __attribute__((ext_vector_type(2)));

// ---------- cross-lane helpers (wave64, DPP) ----------

__device__ __forceinline__ float rl_f(float v, int l) {
  return __builtin_bit_cast(float, __builtin_amdgcn_readlane(__builtin_bit_cast(int, v), l));
}

template <int CTRL, bool BC>
__device__ __forceinline__ float dpp_mv(float oldv, float v) {
  return __builtin_bit_cast(float, __builtin_amdgcn_update_dpp(
      __builtin_bit_cast(int, oldv), __builtin_bit_cast(int, v), CTRL, 0xF, 0xF, BC));
}

__device__ __forceinline__ float wred_max(float v) {
  v = fmaxf(v, dpp_mv<0x128, false>(v, v));
  v = fmaxf(v, dpp_mv<0x124, false>(v, v));
  v = fmaxf(v, dpp_mv<0x122, false>(v, v));
  v = fmaxf(v, dpp_mv<0x121, false>(v, v));
  v = fmaxf(v, dpp_mv<0x142, false>(v, v));
  v = fmaxf(v, dpp_mv<0x143, false>(v, v));
  return rl_f(v, 63);
}

__device__ __forceinline__ float wred_sum(float v) {
  v += dpp_mv<0x128, true>(0.0f, v);
  v += dpp_mv<0x124, true>(0.0f, v);
  v += dpp_mv<0x122, true>(0.0f, v);
  v += dpp_mv<0x121, true>(0.0f, v);
  v += dpp_mv<0x142, true>(0.0f, v);
  v += dpp_mv<0x143, true>(0.0f, v);
  return rl_f(v, 63);
}

__device__ __forceinline__ v2f fma2(v2f a, v2f b, v2f c) {
  return __builtin_elementwise_fma(a, b, c);
}

// dot of broadcast p (s_p[0..47]) with this lane's 24 packed E pairs -> v_pk_fma_f32
__device__ __forceinline__ float dot48(const float4* pv, const v2f* E2) {
  v2f a0 = {0.f, 0.f}, a1 = {0.f, 0.f}, a2 = {0.f, 0.f};
  v2f a3 = {0.f, 0.f}, a4 = {0.f, 0.f}, a5 = {0.f, 0.f};
#pragma unroll
  for (int k = 0; k < 4; ++k) {
    float4 x = pv[3 * k + 0];
    float4 y = pv[3 * k + 1];
    float4 z = pv[3 * k + 2];
    v2f xl = {x.x, x.y}, xh = {x.z, x.w};
    v2f yl = {y.x, y.y}, yh = {y.z, y.w};
    v2f zl = {z.x, z.y}, zh = {z.z, z.w};
    a0 = fma2(xl, E2[6 * k + 0], a0);
    a1 = fma2(xh, E2[6 * k + 1], a1);
    a2 = fma2(yl, E2[6 * k + 2], a2);
    a3 = fma2(yh, E2[6 * k + 3], a3);
    a4 = fma2(zl, E2[6 * k + 4], a4);
    a5 = fma2(zh, E2[6 * k + 5], a5);
  }
  v2f s = ((a0 + a1) + (a2 + a3)) + (a4 + a5);
  return s.x + s.y;
}

// exact pow2 renorm: p *= 2^-e, cl += e*ln2  (3 ALU ops, no rcp/log on chain)
__device__ __forceinline__ void renorm(float& p, float& cl) {
  float mx = wred_max(p);
  int e = ((__builtin_bit_cast(int, mx) >> 23) & 255) - 127;
  float r = __builtin_bit_cast(float, (127 - e) << 23);
  p *= r;
  cl += (float)e * 0.6931471805599453f;
}

// ---------- scan: even block = forward half (t=1..1024 -> alpha_1024),
//                  odd block = backward half (t=2047..1025 -> beta_1024) ----------

extern "C" __global__ __launch_bounds__(64, 1)
void crf_scan(const float* __restrict__ emis,
              const float* __restrict__ trans,
              const float* __restrict__ startt,
              const float* __restrict__ endt,
              const float* __restrict__ mask,
              float* __restrict__ wa, float* __restrict__ wb) {
  __shared__ __align__(16) float s_p[64];
  const int  lane = threadIdx.x;
  const int  bid  = blockIdx.x;
  const int  b    = bid >> 1;
  const bool fwd  = (bid & 1) == 0;
  const int  jc   = lane < NTAGS ? lane : (NTAGS - 1);  // pad lanes mirror lane 47

  const float* eb = emis + (size_t)b * SLEN * NTAGS;
  const float* mb = mask + (size_t)b * SLEN;

  v2f E2[24];  // fwd: column jc of exp(trans) as pairs; bwd: row jc
  if (fwd) {
#pragma unroll
    for (int i = 0; i < 24; ++i) {
      v2f e;
      e.x = __expf(trans[(2 * i + 0) * NTAGS + jc]);
      e.y = __expf(trans[(2 * i + 1) * NTAGS + jc]);
      E2[i] = e;
    }
  } else {
#pragma unroll
    for (int i = 0; i < 24; ++i) {
      v2f e;
      e.x = __expf(trans[jc * NTAGS + 2 * i + 0]);
      e.y = __expf(trans[jc * NTAGS + 2 * i + 1]);
      E2[i] = e;
    }
  }

  const float4* pv = (const float4*)s_p;
  float ebuf[8];  // 8-deep emission prefetch ring, slot = t & 7 (static after unroll)
  float p, cl, een;

  if (fwd) {
    float a0 = startt[jc] + eb[jc];
    if (lane >= NTAGS) a0 = -1e30f;  // pad lanes: p = 0 (never read anyway)
    float m0 = wred_max(a0);
    p  = __expf(a0 - m0);
    cl = m0;
    s_p[lane] = p;
#pragma unroll
    for (int k = 1; k <= 8; ++k) ebuf[k & 7] = eb[(size_t)k * NTAGS + jc];
    een = __expf(ebuf[1]);  // exp(emit_1)

    for (int g = 0; g < 128; ++g) {
#pragma unroll
      for (int u = 0; u < 8; ++u) {
        const int t = 1 + 8 * g + u;
        float ee = een;                          // exp(emit_t), ready (off chain)
        een = __expf(ebuf[(t + 1) & 7]);         // for next step
        float acc = dot48(pv, E2);               // alpha-hat
        float mv  = mb[t];                       // wave-uniform -> s_load
        float pn  = acc * ee;
        p = (mv != 0.0f) ? pn : p;               // masked step = identity
        ebuf[t & 7] = eb[(size_t)(t + 8) * NTAGS + jc];  // prefetch t+8 (<=1032, in-bounds)
        if (u == 7) renorm(p, cl);
        s_p[lane] = p;                           // broadcast for next step
      }
    }
    if (lane < NTAGS) wa[b * NTAGS + lane] = __logf(p) + cl;
  } else {
    float b0 = endt[jc];
    if (lane >= NTAGS) b0 = -1e30f;
    float m0 = wred_max(b0);
    p  = __expf(b0 - m0);
    cl = m0;
#pragma unroll
    for (int k = 0; k < 8; ++k) ebuf[(2047 - k) & 7] = eb[(size_t)(2047 - k) * NTAGS + jc];
    s_p[lane] = p * __expf(ebuf[7]);  // q_2047 = beta_2047 * exp(emit_2047)
    een = __expf(ebuf[6]);            // exp(emit_2046)

    // peel t = 2047..2041 so groups of 8 stay slot-aligned
#pragma unroll
    for (int pt = 0; pt < 7; ++pt) {
      const int t = 2047 - pt;
      float ee = een;                          // exp(emit_{t-1})
      een = __expf(ebuf[(t + 6) & 7]);         // (t-2) & 7
      float acc = dot48(pv, E2);               // beta_{t-1}
      float mv  = mb[t];
      p = (mv != 0.0f) ? acc : p;
      ebuf[t & 7] = eb[(size_t)(t - 8) * NTAGS + jc];
      if (pt == 6) renorm(p, cl);
      s_p[lane] = p * ee;                      // q_{t-1}
    }
    for (int g = 0; g < 127; ++g) {
#pragma unroll
      for (int u = 0; u < 8; ++u) {
        const int t = 2040 - 8 * g - u;        // down to 1025; prefetch >= 1017
        float ee = een;
        een = __expf(ebuf[(t + 6) & 7]);
        float acc = dot48(pv, E2);
        float mv  = mb[t];
        p = (mv != 0.0f) ? acc : p;
        ebuf[t & 7] = eb[(size_t)(t - 8) * NTAGS + jc];
        if (u == 7) renorm(p, cl);
        s_p[lane] = p * ee;
      }
    }
    if (lane < NTAGS) wb[b * NTAGS + lane] = __logf(p) + cl;
  }
}

// ---------- gold-path score + mask count (embarrassingly parallel over (b,t)) ----------

extern "C" __global__ __launch_bounds__(256)
void crf_score(const float* __restrict__ emis,
               const float* __restrict__ trans,
               const float* __restrict__ startt,
               const int*   __restrict__ tags,
               const float* __restrict__ mask,
               float* __restrict__ wsc, int* __restrict__ wcnt) {
  __shared__ float st[NTAGS * NTAGS];
  __shared__ float rs[4], rc[4];
  const int b   = blockIdx.x >> 3;
  const int seg = blockIdx.x & 7;
  const int tid = threadIdx.x;
  for (int k = tid; k < NTAGS * NTAGS; k += 256) st[k] = trans[k];
  __syncthreads();

  const int t = seg * 256 + tid;
  const int* tb = tags + (size_t)b * SLEN;
  float mv  = mask[(size_t)b * SLEN + t];
  int   cur = tb[t];
  float s, c = (mv != 0.0f) ? 1.0f : 0.0f;
  if (t == 0) {
    s = startt[cur] + emis[(size_t)b * SLEN * NTAGS + cur];  // unmasked per reference
  } else {
    int prev = tb[t - 1];
    float ev = emis[((size_t)b * SLEN + t) * NTAGS + cur];
    s = (mv != 0.0f) ? (st[prev * NTAGS + cur] + ev) : 0.0f;
  }
  float ws_ = wred_sum(s);
  float wc_ = wred_sum(c);
  const int wid = tid >> 6;
  if ((tid & 63) == 0) { rs[wid] = ws_; rc[wid] = wc_; }
  __syncthreads();
  if (tid == 0) {
    wsc[blockIdx.x]  = rs[0] + rs[1] + rs[2] + rs[3];
    wcnt[blockIdx.x] = (int)(rc[0] + rc[1] + rc[2] + rc[3] + 0.5f);
  }
}

// ---------- combine: partition_b = lse(alpha_1024 + beta_1024); loss ----------

extern "C" __global__ __launch_bounds__(64)
void crf_combine(const float* __restrict__ wa, const float* __restrict__ wb,
                 const float* __restrict__ wsc, const int* __restrict__ wcnt,
                 const int* __restrict__ tags, const float* __restrict__ endt,
                 float* __restrict__ out) {
  const int b    = blockIdx.x;
  const int lane = threadIdx.x;
  float v = -1e30f;
  if (lane < NTAGS) v = wa[b * NTAGS + lane] + wb[b * NTAGS + lane];
  float m = wred_max(v);
  float s = wred_sum(__expf(v - m));
  float part = m + __logf(s);
  float sc = (lane < 8) ? wsc[b * 8 + lane] : 0.0f;
  float cf = (lane < 8) ? (float)wcnt[b * 8 + lane] : 0.0f;
  sc = wred_sum(sc);
  cf = wred_sum(cf);
  int last = (int)(cf + 0.5f) - 1;
  float score = sc + endt[tags[(size_t)b * SLEN + last]];
  if (lane == 0) atomicAdd(out, (part - score) * (1.0f / (float)NB));
}

// ---------- launch ----------

extern "C" void kernel_launch(void* const* d_in, const int* in_sizes, int n_in,
                              void* d_out, int out_size, void* d_ws, size_t ws_size,
                              hipStream_t stream) {
  const float* emis  = (const float*)d_in[0];
  const float* trans = (const float*)d_in[1];
  const float* stt   = (const float*)d_in[2];
  const float* ent   = (const float*)d_in[3];
  const int*   tags  = (const int*)d_in[4];
  const float* mask  = (const float*)d_in[5];

  float* wa   = (float*)d_ws;            // [NB][NTAGS]
  float* wb   = wa + NB * NTAGS;         // [NB][NTAGS]
  float* wsc  = wb + NB * NTAGS;         // [NB*8] score partials
  int*   wcnt = (int*)(wsc + NB * 8);    // [NB*8] mask counts

  hipMemsetAsync(d_out, 0, sizeof(float), stream);
  crf_scan<<<2 * NB, 64, 0, stream>>>(emis, trans, stt, ent, mask, wa, wb);
  crf_score<<<NB * 8, 256, 0, stream>>>(emis, trans, stt, tags, mask, wsc, wcnt);
  crf_combine<<<NB, 64, 0, stream>>>(wa, wb, wsc, wcnt, tags, ent, (float*)d_out);
}

// Round 3
// 425.356 us; speedup vs baseline: 1.6659x; 1.1319x over previous
//
#include <hip/hip_runtime.h>

#define NTAGS 48
#define NB    512
#define SLEN  2048

// ---------- cross-lane helpers (wave64, DPP) ----------

__device__ __forceinline__ float rl_f(float v, int l) {
  return __builtin_bit_cast(float, __builtin_amdgcn_readlane(__builtin_bit_cast(int, v), l));
}

template <int CTRL, bool BC>
__device__ __forceinline__ float dpp_mv(float oldv, float v) {
  return __builtin_bit_cast(float, __builtin_amdgcn_update_dpp(
      __builtin_bit_cast(int, oldv), __builtin_bit_cast(int, v), CTRL, 0xF, 0xF, BC));
}

__device__ __forceinline__ float wred_max(float v) {
  v = fmaxf(v, dpp_mv<0x128, false>(v, v));
  v = fmaxf(v, dpp_mv<0x124, false>(v, v));
  v = fmaxf(v, dpp_mv<0x122, false>(v, v));
  v = fmaxf(v, dpp_mv<0x121, false>(v, v));
  v = fmaxf(v, dpp_mv<0x142, false>(v, v));
  v = fmaxf(v, dpp_mv<0x143, false>(v, v));
  return rl_f(v, 63);
}

__device__ __forceinline__ float wred_sum(float v) {
  v += dpp_mv<0x128, true>(0.0f, v);
  v += dpp_mv<0x124, true>(0.0f, v);
  v += dpp_mv<0x122, true>(0.0f, v);
  v += dpp_mv<0x121, true>(0.0f, v);
  v += dpp_mv<0x142, true>(0.0f, v);
  v += dpp_mv<0x143, true>(0.0f, v);
  return rl_f(v, 63);
}

// broadcast-dot: y = sum_{i<48} v[i] * Ev[i], where v is one value per lane.
// 48 v_readlane (lane-const) -> SGPRs, 48 v_fmac with SGPR src0. No LDS.
__device__ __forceinline__ float rdot48(float v, const float* Ev) {
  float a0 = 0.f, a1 = 0.f, a2 = 0.f, a3 = 0.f;
#pragma unroll
  for (int i = 0; i < NTAGS; i += 4) {
    a0 = fmaf(rl_f(v, i + 0), Ev[i + 0], a0);
    a1 = fmaf(rl_f(v, i + 1), Ev[i + 1], a1);
    a2 = fmaf(rl_f(v, i + 2), Ev[i + 2], a2);
    a3 = fmaf(rl_f(v, i + 3), Ev[i + 3], a3);
  }
  return (a0 + a1) + (a2 + a3);
}

// exact pow2 renorm: p *= 2^-e, cl += e*ln2
__device__ __forceinline__ void renorm(float& p, float& cl) {
  float mx = wred_max(p);
  int e = ((__builtin_bit_cast(int, mx) >> 23) & 255) - 127;
  float r = __builtin_bit_cast(float, (127 - e) << 23);
  p *= r;
  cl += (float)e * 0.6931471805599453f;
}

// ---------- fused kernel ----------
// blocks [0,1024): scan. even = forward half (alpha_1024), odd = backward half (beta_1024).
// blocks [1024,1536): gold-path score + mask count, one wave per batch.

extern "C" __global__ __launch_bounds__(64, 1)
void crf_main(const float* __restrict__ emis,
              const float* __restrict__ trans,
              const float* __restrict__ startt,
              const float* __restrict__ endt,
              const int*   __restrict__ tags,
              const float* __restrict__ mask,
              float* __restrict__ wa, float* __restrict__ wb,
              float* __restrict__ wsc, int* __restrict__ wcnt) {
  __shared__ float st[NTAGS * NTAGS];
  const int lane = threadIdx.x;
  const int bid  = blockIdx.x;

  if (bid >= 2 * NB) {
    // ----- score path -----
    const int b = bid - 2 * NB;
    for (int k = lane; k < NTAGS * NTAGS; k += 64) st[k] = trans[k];
    __syncthreads();
    const int* tb = tags + (size_t)b * SLEN;
    float ssum = 0.0f, csum = 0.0f;
    for (int it = 0; it < SLEN / 64; ++it) {
      const int t   = it * 64 + lane;
      int   cur = tb[t];
      float mv  = mask[(size_t)b * SLEN + t];
      float ev  = emis[((size_t)b * SLEN + t) * NTAGS + cur];
      float s;
      if (t == 0) {
        s = startt[cur] + ev;  // unmasked per reference
      } else {
        int prev = tb[t - 1];
        s = (mv != 0.0f) ? (st[prev * NTAGS + cur] + ev) : 0.0f;
      }
      ssum += s;
      csum += (mv != 0.0f) ? 1.0f : 0.0f;
    }
    ssum = wred_sum(ssum);
    csum = wred_sum(csum);
    if (lane == 0) { wsc[b] = ssum; wcnt[b] = (int)(csum + 0.5f); }
    return;
  }

  // ----- scan path -----
  const int  b   = bid >> 1;
  const bool fwd = (bid & 1) == 0;
  const int  jc  = lane < NTAGS ? lane : (NTAGS - 1);  // pad lanes mirror lane 47

  const float* eb = emis + (size_t)b * SLEN * NTAGS;
  const float* mb = mask + (size_t)b * SLEN;

  float Ev[NTAGS];  // fwd: lane j holds column j of exp(trans); bwd: lane i holds row i
  if (fwd) {
#pragma unroll
    for (int i = 0; i < NTAGS; ++i) Ev[i] = __expf(trans[i * NTAGS + jc]);
  } else {
#pragma unroll
    for (int j = 0; j < NTAGS; ++j) Ev[j] = __expf(trans[jc * NTAGS + j]);
  }

  float ebuf[8];  // 8-deep emission prefetch ring, slot = t & 7
  float p, cl, een;

  if (fwd) {
    float a0 = startt[jc] + eb[jc];
    if (lane >= NTAGS) a0 = -1e30f;
    float m0 = wred_max(a0);
    p  = __expf(a0 - m0);   // pad lanes duplicate lane 47's column -> p_pad == p_47, harmless
    cl = m0;
#pragma unroll
    for (int k = 1; k <= 8; ++k) ebuf[k & 7] = eb[(size_t)k * NTAGS + jc];
    een = __expf(ebuf[1]);  // exp(emit_1)

    for (int g = 0; g < 128; ++g) {
#pragma unroll
      for (int u = 0; u < 8; ++u) {
        const int t = 1 + 8 * g + u;
        float ee = een;                       // exp(emit_t), off-chain
        een = __expf(ebuf[(t + 1) & 7]);
        float acc = rdot48(p, Ev);            // alpha-hat via readlane broadcast
        float mv  = mb[t];                    // wave-uniform -> scalar load
        float pn  = acc * ee;
        p = (mv != 0.0f) ? pn : p;
        ebuf[t & 7] = eb[(size_t)(t + 8) * NTAGS + jc];  // prefetch t+8
        if (u == 7) renorm(p, cl);
      }
    }
    if (lane < NTAGS) wa[b * NTAGS + lane] = __logf(p) + cl;
  } else {
    float b0 = endt[jc];
    if (lane >= NTAGS) b0 = -1e30f;
    float m0 = wred_max(b0);
    p  = __expf(b0 - m0);
    cl = m0;
#pragma unroll
    for (int k = 0; k < 8; ++k) ebuf[(2047 - k) & 7] = eb[(size_t)(2047 - k) * NTAGS + jc];
    float q = p * __expf(ebuf[7]);  // q_2047 = beta_2047 * exp(emit_2047)
    een = __expf(ebuf[6]);          // exp(emit_2046)

    // peel t = 2047..2041 to align groups of 8
#pragma unroll
    for (int pt = 0; pt < 7; ++pt) {
      const int t = 2047 - pt;
      float ee = een;                       // exp(emit_{t-1})
      een = __expf(ebuf[(t + 6) & 7]);      // emit_{t-2}
      float acc = rdot48(q, Ev);            // beta_{t-1}
      float mv  = mb[t];
      p = (mv != 0.0f) ? acc : p;
      ebuf[t & 7] = eb[(size_t)(t - 8) * NTAGS + jc];
      if (pt == 6) renorm(p, cl);
      q = p * ee;
    }
    for (int g = 0; g < 127; ++g) {
#pragma unroll
      for (int u = 0; u < 8; ++u) {
        const int t = 2040 - 8 * g - u;     // down to 1025
        float ee = een;
        een = __expf(ebuf[(t + 6) & 7]);
        float acc = rdot48(q, Ev);
        float mv  = mb[t];
        p = (mv != 0.0f) ? acc : p;
        ebuf[t & 7] = eb[(size_t)(t - 8) * NTAGS + jc];
        if (u == 7) renorm(p, cl);
        q = p * ee;
      }
    }
    if (lane < NTAGS) wb[b * NTAGS + lane] = __logf(p) + cl;
  }
}

// ---------- combine: partition_b = lse(alpha_1024 + beta_1024); loss ----------

extern "C" __global__ __launch_bounds__(64)
void crf_combine(const float* __restrict__ wa, const float* __restrict__ wb,
                 const float* __restrict__ wsc, const int* __restrict__ wcnt,
                 const int* __restrict__ tags, const float* __restrict__ endt,
                 float* __restrict__ out) {
  const int b    = blockIdx.x;
  const int lane = threadIdx.x;
  float v = -1e30f;
  if (lane < NTAGS) v = wa[b * NTAGS + lane] + wb[b * NTAGS + lane];
  float m = wred_max(v);
  float s = wred_sum(__expf(v - m));
  float part = m + __logf(s);
  int   last = wcnt[b] - 1;
  float score = wsc[b] + endt[tags[(size_t)b * SLEN + last]];
  if (lane == 0) atomicAdd(out, (part - score) * (1.0f / (float)NB));
}

// ---------- launch ----------

extern "C" void kernel_launch(void* const* d_in, const int* in_sizes, int n_in,
                              void* d_out, int out_size, void* d_ws, size_t ws_size,
                              hipStream_t stream) {
  const float* emis  = (const float*)d_in[0];
  const float* trans = (const float*)d_in[1];
  const float* stt   = (const float*)d_in[2];
  const float* ent   = (const float*)d_in[3];
  const int*   tags  = (const int*)d_in[4];
  const float* mask  = (const float*)d_in[5];

  float* wa   = (float*)d_ws;            // [NB][NTAGS]
  float* wb   = wa + NB * NTAGS;         // [NB][NTAGS]
  float* wsc  = wb + NB * NTAGS;         // [NB]
  int*   wcnt = (int*)(wsc + NB);        // [NB]

  hipMemsetAsync(d_out, 0, sizeof(float), stream);
  crf_main<<<2 * NB + NB, 64, 0, stream>>>(emis, trans, stt, ent, tags, mask,
                                           wa, wb, wsc, wcnt);
  crf_combine<<<NB, 64, 0, stream>>>(wa, wb, wsc, wcnt, tags, ent, (float*)d_out);
}